// Round 4
// baseline (261.897 us; speedup 1.0000x reference)
//
#include <hip/hip_runtime.h>

#define G_VOX  68921      // 41^3
#define GMAX   68920      // last valid element index
#define NSEG   272        // segment-table entries (270 real + 2 padding)
#define NRSEG  270        // ceil(17230 quads / 64) segments of 256 elements
#define MWORDS 2176       // 32-bit sphere-mask words (69632 bits)
#define RMQ_N  4320       // 270*16 ushort entries per phase
#define NEGV (-1.0e9f)
#define VTH  (-1.0e8f)

__device__ __forceinline__ bool sphere_bit(const float* __restrict__ gxyz, int e) {
    if (e >= G_VOX || e < 0) return false;
    float gx = gxyz[e * 3 + 0];
    float gy = gxyz[e * 3 + 1];
    float gz = gxyz[e * 3 + 2];
    float s  = __fadd_rn(__fadd_rn(__fmul_rn(gx, gx), __fmul_rn(gy, gy)),
                         __fmul_rn(gz, gz));
    return (__fsqrt_rn(s) <= 6.0f);   // bit-matches np.linalg.norm(grid_xyz) <= 6
}

// ---------------- Kernel 0: sphere word-mask + 4 phase-repacked ushort tables ----------------
__global__ __launch_bounds__(256) void build_mask(
    const float* __restrict__ gxyz,
    unsigned int* __restrict__ mask,         // [MWORDS] natural bit order
    unsigned short* __restrict__ rmq)        // [4][RMQ_N] bit(j*4+u) = sphere(h + s*256 + 4p + 64j + u)
{
    const int tid  = threadIdx.x;
    const int lane = tid & 63;
    {
        int idx = blockIdx.x * 256 + tid;    // 0..69631
        unsigned long long bal = __ballot(sphere_bit(gxyz, idx));
        if (lane == 0)       mask[idx >> 5] = (unsigned int)bal;
        else if (lane == 32) mask[idx >> 5] = (unsigned int)(bal >> 32);
    }
    int gid = blockIdx.x * 256 + tid;
    if (gid < 4 * RMQ_N) {
        int h   = gid / RMQ_N;
        int rem = gid - h * RMQ_N;
        int s   = rem >> 4;
        int p   = rem & 15;
        int base = h + s * 256 + 4 * p;
        unsigned int bits = 0;
        #pragma unroll
        for (int j = 0; j < 4; ++j)
            #pragma unroll
            for (int u = 0; u < 4; ++u)
                if (sphere_bit(gxyz, base + 64 * j + u)) bits |= 1u << (j * 4 + u);
        rmq[gid] = (unsigned short)bits;
    }
}

// ---------------- Kernel 1: per-256-segment masked argmax, aligned float4 loads ----------------
__global__ __launch_bounds__(256) void seg_max(
    const float* __restrict__ density, const unsigned short* __restrict__ rmq,
    float* __restrict__ svals, int* __restrict__ sidxs)
{
    const int nc  = blockIdx.x;               // 0..511
    const int c   = blockIdx.y;               // 0..16
    const int tid = threadIdx.x;
    const int p   = tid & 15;
    const int sl  = tid >> 4;
    const int s   = c * 16 + sl;
    const int h   = (-nc) & 3;                // phase: global idx nc*68921+e aligned when e==h mod 4
    const float* dens = density + (size_t)nc * G_VOX;

    const unsigned int bits = (s < NRSEG) ? (unsigned int)rmq[h * RMQ_N + s * 16 + p] : 0u;
    const int base = h + s * 256 + 4 * p;

    float bv = NEGV;
    int   bi = base;
    if (c < 16) {                              // fully in-bounds: max e = h+65535+3 <= 65539
        #pragma unroll
        for (int j = 0; j < 4; ++j) {
            int e = base + 64 * j;
            float4 d = *reinterpret_cast<const float4*>(dens + e);
            float v0 = ((bits >> (j * 4 + 0)) & 1u) ? d.x : NEGV;
            float v1 = ((bits >> (j * 4 + 1)) & 1u) ? d.y : NEGV;
            float v2 = ((bits >> (j * 4 + 2)) & 1u) ? d.z : NEGV;
            float v3 = ((bits >> (j * 4 + 3)) & 1u) ? d.w : NEGV;
            if (v0 > bv) { bv = v0; bi = e;     }   // ascending e + strict > = first occurrence
            if (v1 > bv) { bv = v1; bi = e + 1; }
            if (v2 > bv) { bv = v2; bi = e + 2; }
            if (v3 > bv) { bv = v3; bi = e + 3; }
        }
    } else {
        #pragma unroll
        for (int j = 0; j < 4; ++j) {
            int e = base + 64 * j;
            if (e + 3 <= GMAX) {
                float4 d = *reinterpret_cast<const float4*>(dens + e);
                float v0 = ((bits >> (j * 4 + 0)) & 1u) ? d.x : NEGV;
                float v1 = ((bits >> (j * 4 + 1)) & 1u) ? d.y : NEGV;
                float v2 = ((bits >> (j * 4 + 2)) & 1u) ? d.z : NEGV;
                float v3 = ((bits >> (j * 4 + 3)) & 1u) ? d.w : NEGV;
                if (v0 > bv) { bv = v0; bi = e;     }
                if (v1 > bv) { bv = v1; bi = e + 1; }
                if (v2 > bv) { bv = v2; bi = e + 2; }
                if (v3 > bv) { bv = v3; bi = e + 3; }
            } else {
                #pragma unroll
                for (int u = 0; u < 4; ++u) {
                    if ((bits >> (j * 4 + u)) & 1u) {   // bit set implies e+u <= GMAX
                        float v = dens[e + u];
                        if (v > bv) { bv = v; bi = e + u; }
                    }
                }
            }
        }
    }
    // butterfly over the 16 lanes of this segment, tie-break lowest index
    #pragma unroll
    for (int off = 1; off < 16; off <<= 1) {
        float ov = __shfl_xor(bv, off);
        int   oi = __shfl_xor(bi, off);
        if (ov > bv || (ov == bv && oi < bi)) { bv = ov; bi = oi; }
    }
    if (p == 0) {
        svals[nc * NSEG + s] = bv;
        sidxs[nc * NSEG + s] = bi;
    }
}

// ---------------- Kernel 2: K=4 rounds of argmax + analytic NMS recompute ----------------
__global__ __launch_bounds__(256) void pick_peaks(
    const float* __restrict__ density,
    const float* __restrict__ gxyz,
    const unsigned int* __restrict__ maskg,
    const float* __restrict__ svals, const int* __restrict__ sidxs,
    const float* __restrict__ Rm, const float* __restrict__ tp,
    const float* __restrict__ nmask,
    float* __restrict__ out)
{
    __shared__ float sval[NSEG];
    __shared__ int   sidx[NSEG];
    __shared__ int   flag[NSEG];
    __shared__ int   list[104];
    __shared__ int   nlist;
    __shared__ float rv[4];
    __shared__ int   ri[4];
    __shared__ float pval[4];
    __shared__ int   pidx[4];
    __shared__ int   pki[4], pkj[4], pkk[4];

    const int tid = threadIdx.x;
    const int nc  = blockIdx.x;
    const int n   = nc >> 2;
    const int h   = (-nc) & 3;
    const float* dens = density + (size_t)nc * G_VOX;

    for (int i = tid; i < NSEG; i += 256) {
        sval[i] = svals[nc * NSEG + i];
        sidx[i] = sidxs[nc * NSEG + i];
        flag[i] = 0;
    }
    __syncthreads();

    for (int p = 0; p < 4; ++p) {
        // global argmax over segment records (tie-break: lowest voxel index)
        float bv = -INFINITY;
        int   bi = 0x7FFFFFFF;
        for (int s = tid; s < NSEG; s += 256) {
            float v = sval[s];
            int   i = sidx[s];
            if (v > bv || (v == bv && i < bi)) { bv = v; bi = i; }
        }
        for (int off = 32; off > 0; off >>= 1) {
            float ov = __shfl_down(bv, off);
            int   oi = __shfl_down(bi, off);
            if (ov > bv || (ov == bv && oi < bi)) { bv = ov; bi = oi; }
        }
        if ((tid & 63) == 0) { rv[tid >> 6] = bv; ri[tid >> 6] = bi; }
        __syncthreads();
        if (tid == 0) {
            for (int w = 1; w < 4; ++w)
                if (rv[w] > bv || (rv[w] == bv && ri[w] < bi)) { bv = rv[w]; bi = ri[w]; }
            pval[p] = bv;
            pidx[p] = bi;
            int pi = bi / 1681;
            int rr = bi - pi * 1681;
            int pj = rr / 41;
            pki[p] = pi; pkj[p] = pj; pkk[p] = rr - pj * 41;
            nlist = 0;
        }
        __syncthreads();

        if (p < 3 && pval[p] > VTH) {
            // flag segments containing any voxel of the 7x7x7 Chebyshev cube
            if (tid < 49) {
                int di = tid / 7 - 3, dj = tid % 7 - 3;
                int ii = pki[p] + di, jj = pkj[p] + dj;
                if (ii >= 0 && ii <= 40 && jj >= 0 && jj <= 40) {
                    int k0 = pkk[p] - 3; if (k0 < 0)  k0 = 0;
                    int k1 = pkk[p] + 3; if (k1 > 40) k1 = 40;
                    int b0 = ii * 1681 + jj * 41 + k0;
                    int b1 = b0 + (k1 - k0);
                    int s0 = (b0 > h) ? (b0 - h) >> 8 : 0;
                    int s1 = (b1 > h) ? (b1 - h) >> 8 : 0;
                    if (atomicMax(&flag[s0], p + 1) < p + 1) {
                        int q = atomicAdd(&nlist, 1); list[q] = s0;
                    }
                    if (s1 != s0 && atomicMax(&flag[s1], p + 1) < p + 1) {
                        int q = atomicAdd(&nlist, 1); list[q] = s1;
                    }
                }
            }
            __syncthreads();
            // recompute flagged segments: validity = sphere AND not within Chebyshev<=3 of peaks 0..p
            const int lane = tid & 63;
            const int w    = tid >> 6;
            const int cnt  = nlist;
            for (int j = w; j < cnt; j += 4) {
                int s  = list[j];
                int e0 = h + s * 256 + 4 * lane;
                bool vec = (e0 + 3 <= GMAX);
                float4 d = make_float4(0.f, 0.f, 0.f, 0.f);
                if (vec) d = *reinterpret_cast<const float4*>(dens + e0);
                float bv2 = NEGV;
                int   bi2 = e0;
                #pragma unroll
                for (int u = 0; u < 4; ++u) {
                    int e = e0 + u;
                    if (e <= GMAX) {
                        unsigned int wrd = maskg[e >> 5];
                        if ((wrd >> (e & 31)) & 1u) {
                            int ei = e / 1681;
                            int er = e - ei * 1681;
                            int ej = er / 41;
                            int ek = er - ej * 41;
                            bool sup = false;
                            for (int q = 0; q <= p; ++q) {
                                if (pval[q] > VTH) {
                                    int ai = abs(ei - pki[q]);
                                    int aj = abs(ej - pkj[q]);
                                    int ak = abs(ek - pkk[q]);
                                    int m = ai > aj ? ai : aj; m = m > ak ? m : ak;
                                    if (m <= 3) sup = true;
                                }
                            }
                            if (!sup) {
                                float v = vec ? (u == 0 ? d.x : u == 1 ? d.y : u == 2 ? d.z : d.w)
                                              : dens[e];
                                if (v > bv2) { bv2 = v; bi2 = e; }
                            }
                        }
                    }
                }
                for (int off = 32; off > 0; off >>= 1) {
                    float ov = __shfl_down(bv2, off);
                    int   oi = __shfl_down(bi2, off);
                    if (ov > bv2 || (ov == bv2 && oi < bi2)) { bv2 = ov; bi2 = oi; }
                }
                if (lane == 0) { sval[s] = bv2; sidx[s] = bi2; }
            }
        }
        __syncthreads();
    }

    // ---- epilogue: one peak per thread ----
    if (tid < 4) {
        const int k   = tid;
        const float val = pval[k];
        const int   idx = pidx[k];
        const bool valid = val > VTH;
        float gx = 0.0f, gy = 0.0f, gz = 0.0f;
        if (valid) {
            gx = gxyz[idx * 3 + 0];
            gy = gxyz[idx * 3 + 1];
            gz = gxyz[idx * 3 + 2];
        }
        const float nm = nmask[n];
        const float* R = Rm + n * 9;
        const float* t = tp + n * 3;
        float wx = R[0] * gx + R[1] * gy + R[2] * gz + t[0];
        float wy = R[3] * gx + R[4] * gy + R[5] * gz + t[1];
        float wz = R[6] * gx + R[7] * gy + R[8] * gz + t[2];

        const size_t o3 = ((size_t)nc * 4 + k) * 3;
        out[o3 + 0] = gx * nm;
        out[o3 + 1] = gy * nm;
        out[o3 + 2] = gz * nm;
        out[6144 + o3 + 0] = wx * nm;
        out[6144 + o3 + 1] = wy * nm;
        out[6144 + o3 + 2] = wz * nm;
        const size_t o1 = (size_t)nc * 4 + k;
        out[12288 + o1] = (valid ? val : NEGV) * nm;
        out[14336 + o1] = (valid && nm != 0.0f) ? 1.0f : 0.0f;
    }
}

extern "C" void kernel_launch(void* const* d_in, const int* in_sizes, int n_in,
                              void* d_out, int out_size, void* d_ws, size_t ws_size,
                              hipStream_t stream) {
    const float* density  = (const float*)d_in[0];  // [1,128,4,G] f32
    const float* grid_xyz = (const float*)d_in[1];  // [G,3] f32
    const float* Rm    = (const float*)d_in[4];     // [1,128,3,3] f32
    const float* tpos  = (const float*)d_in[5];     // [1,128,3] f32
    const float* nmask = (const float*)d_in[6];     // [1,128] f32
    float* out = (float*)d_out;                     // 16384 f32

    // workspace layout
    unsigned int*   mask = (unsigned int*)d_ws;                        // 8704 B
    unsigned short* rmq  = (unsigned short*)((char*)d_ws + 8704);      // 4*4320*2 = 34560 B
    float* svals = (float*)((char*)d_ws + 43264);                      // 512*272*4 = 557056 B
    int*   sidxs = (int*)  ((char*)d_ws + 600320);                     // 512*272*4

    build_mask<<<dim3(272), dim3(256), 0, stream>>>(grid_xyz, mask, rmq);
    seg_max<<<dim3(512, 17), dim3(256), 0, stream>>>(density, rmq, svals, sidxs);
    pick_peaks<<<dim3(512), dim3(256), 0, stream>>>(density, grid_xyz, mask,
                                                    svals, sidxs, Rm, tpos, nmask, out);
}

// Round 5
// 229.588 us; speedup vs baseline: 1.1407x; 1.1407x over previous
//
#include <hip/hip_runtime.h>

#define G_VOX  68921      // 41^3
#define GMAX   68920      // last valid element index
#define NSEG   272        // 272 segments of 256 elements (phase-shifted); last 2 are padding
#define MWORDS 2176       // 32-bit sphere-mask words (69632 bits)
#define NEGV (-1.0e9f)
#define VTH  (-1.0e8f)

__device__ __forceinline__ bool sphere_bit(const float* __restrict__ gxyz, int e) {
    if (e >= G_VOX) return false;
    float gx = gxyz[e * 3 + 0];
    float gy = gxyz[e * 3 + 1];
    float gz = gxyz[e * 3 + 2];
    float s  = __fadd_rn(__fadd_rn(__fmul_rn(gx, gx), __fmul_rn(gy, gy)),
                         __fmul_rn(gz, gz));
    return (__fsqrt_rn(s) <= 6.0f);   // bit-matches np.linalg.norm(grid_xyz) <= 6
}

// ---------------- Kernel 0: sphere word-mask ----------------
__global__ __launch_bounds__(256) void build_mask(
    const float* __restrict__ gxyz, unsigned int* __restrict__ mask)
{
    int idx = blockIdx.x * 256 + threadIdx.x;    // 0..69631
    unsigned long long bal = __ballot(sphere_bit(gxyz, idx));
    int lane = threadIdx.x & 63;
    if (lane == 0)       mask[idx >> 5] = (unsigned int)bal;
    else if (lane == 32) mask[idx >> 5] = (unsigned int)(bal >> 32);
}

// ---------------- Fused kernel: one density pass + K=4 pick/NMS, one block per nc ----------------
__global__ __launch_bounds__(512) void fused_peaks(
    const float* __restrict__ density,
    const float* __restrict__ gxyz,
    const unsigned int* __restrict__ maskg,
    const float* __restrict__ Rm, const float* __restrict__ tp,
    const float* __restrict__ nmask,
    float* __restrict__ out)
{
    __shared__ unsigned int smask[MWORDS + 2];   // +2: 64-bit extracts may touch word wd+1
    __shared__ float sval[NSEG];
    __shared__ int   sidx[NSEG];
    __shared__ int   flag[NSEG];
    __shared__ int   list[104];
    __shared__ int   nlist;
    __shared__ float rv[8];
    __shared__ int   ri[8];
    __shared__ float pval[4];
    __shared__ int   pidx[4];
    __shared__ int   pki[4], pkj[4], pkk[4];

    const int tid  = threadIdx.x;
    const int nc   = blockIdx.x;                 // 0..511
    const int n    = nc >> 2;
    const int h    = (-nc) & 3;                  // phase: nc*68921 + h == 0 (mod 4)
    const int lane = tid & 63;
    const int w    = tid >> 6;                   // wave 0..7
    const float* dens = density + (size_t)nc * G_VOX;

    for (int i = tid; i < MWORDS + 2; i += 512) smask[i] = (i < MWORDS) ? maskg[i] : 0u;
    for (int i = tid; i < NSEG; i += 512) flag[i] = 0;
    __syncthreads();

    // ---- single density pass: wave w computes segment s = w + 8j at step j ----
    // lane l covers elements e = h + 256*s + 4*l .. +3 (16B-aligned float4)
    for (int j = 0; j < 34; ++j) {
        const int s = w + 8 * j;                 // 0..271, each exactly once
        const int e = h + 4 * tid + 2048 * j;    // == h + 256*s + 4*lane
        const int wd = e >> 5, sh = e & 31;
        unsigned long long mw = ((unsigned long long)smask[wd + 1] << 32) | smask[wd];
        const unsigned int bits = (unsigned int)(mw >> sh) & 0xFu;

        float bv = NEGV;
        int   bi = e;
        if (bits) {
            if (e + 3 <= GMAX) {
                float4 d = *reinterpret_cast<const float4*>(dens + e);
                float v0 = (bits & 1u) ? d.x : NEGV;
                float v1 = (bits & 2u) ? d.y : NEGV;
                float v2 = (bits & 4u) ? d.z : NEGV;
                float v3 = (bits & 8u) ? d.w : NEGV;
                if (v0 > bv) { bv = v0; bi = e;     }   // ascending e + strict > = first occurrence
                if (v1 > bv) { bv = v1; bi = e + 1; }
                if (v2 > bv) { bv = v2; bi = e + 2; }
                if (v3 > bv) { bv = v3; bi = e + 3; }
            } else {
                #pragma unroll
                for (int u = 0; u < 4; ++u) {
                    if (((bits >> u) & 1u) && e + u <= GMAX) {
                        float v = dens[e + u];
                        if (v > bv) { bv = v; bi = e + u; }
                    }
                }
            }
        }
        // 64-lane reduce, tie-break lowest index
        #pragma unroll
        for (int off = 32; off > 0; off >>= 1) {
            float ov = __shfl_down(bv, off);
            int   oi = __shfl_down(bi, off);
            if (ov > bv || (ov == bv && oi < bi)) { bv = ov; bi = oi; }
        }
        if (lane == 0) { sval[s] = bv; sidx[s] = bi; }
    }
    __syncthreads();

    // ---- K=4 rounds: table argmax + LDS-mask suppression + segment recompute ----
    for (int p = 0; p < 4; ++p) {
        float bv = -INFINITY;
        int   bi = 0x7FFFFFFF;
        if (tid < NSEG) { bv = sval[tid]; bi = sidx[tid]; }
        #pragma unroll
        for (int off = 32; off > 0; off >>= 1) {
            float ov = __shfl_down(bv, off);
            int   oi = __shfl_down(bi, off);
            if (ov > bv || (ov == bv && oi < bi)) { bv = ov; bi = oi; }
        }
        if (lane == 0) { rv[w] = bv; ri[w] = bi; }
        __syncthreads();
        if (w == 0) {
            bv = (lane < 8) ? rv[lane] : -INFINITY;
            bi = (lane < 8) ? ri[lane] : 0x7FFFFFFF;
            #pragma unroll
            for (int off = 4; off > 0; off >>= 1) {
                float ov = __shfl_down(bv, off);
                int   oi = __shfl_down(bi, off);
                if (ov > bv || (ov == bv && oi < bi)) { bv = ov; bi = oi; }
            }
            if (lane == 0) {
                pval[p] = bv;
                pidx[p] = bi;
                int pi = bi / 1681;
                int rr = bi - pi * 1681;
                int pj = rr / 41;
                pki[p] = pi; pkj[p] = pj; pkk[p] = rr - pj * 41;
                nlist = 0;
            }
        }
        __syncthreads();

        if (p < 3 && pval[p] > VTH) {
            // clear 7x7x7 Chebyshev cube bits in LDS mask; collect affected segments
            if (tid < 49) {
                int di = tid / 7 - 3, dj = tid % 7 - 3;
                int ii = pki[p] + di, jj = pkj[p] + dj;
                if (ii >= 0 && ii <= 40 && jj >= 0 && jj <= 40) {
                    int k0 = pkk[p] - 3; if (k0 < 0)  k0 = 0;
                    int k1 = pkk[p] + 3; if (k1 > 40) k1 = 40;
                    int b0  = ii * 1681 + jj * 41 + k0;
                    int cnt = k1 - k0 + 1;
                    unsigned long long m = ((1ull << cnt) - 1ull) << (b0 & 31);
                    int w0 = b0 >> 5;
                    atomicAnd(&smask[w0], ~(unsigned int)m);
                    unsigned int hi = (unsigned int)(m >> 32);
                    if (hi) atomicAnd(&smask[w0 + 1], ~hi);
                    // phase-shifted segment ids containing this run
                    int s0 = (b0 > h) ? (b0 - h) >> 8 : 0;
                    int s1 = (b0 + cnt - 1 > h) ? (b0 + cnt - 1 - h) >> 8 : 0;
                    if (atomicMax(&flag[s0], p + 1) < p + 1) {
                        int q = atomicAdd(&nlist, 1); list[q] = s0;
                    }
                    if (s1 != s0 && atomicMax(&flag[s1], p + 1) < p + 1) {
                        int q = atomicAdd(&nlist, 1); list[q] = s1;
                    }
                }
            }
            __syncthreads();
            // recompute flagged segments: one wave per list entry
            const int cnt = nlist;
            for (int q = w; q < cnt; q += 8) {
                const int s = list[q];
                const int e = h + 256 * s + 4 * lane;
                const int wd = e >> 5, sh = e & 31;
                unsigned long long mw = ((unsigned long long)smask[wd + 1] << 32) | smask[wd];
                const unsigned int bits = (unsigned int)(mw >> sh) & 0xFu;
                float bv2 = NEGV;
                int   bi2 = e;
                if (bits) {
                    if (e + 3 <= GMAX) {
                        float4 d = *reinterpret_cast<const float4*>(dens + e);
                        float v0 = (bits & 1u) ? d.x : NEGV;
                        float v1 = (bits & 2u) ? d.y : NEGV;
                        float v2 = (bits & 4u) ? d.z : NEGV;
                        float v3 = (bits & 8u) ? d.w : NEGV;
                        if (v0 > bv2) { bv2 = v0; bi2 = e;     }
                        if (v1 > bv2) { bv2 = v1; bi2 = e + 1; }
                        if (v2 > bv2) { bv2 = v2; bi2 = e + 2; }
                        if (v3 > bv2) { bv2 = v3; bi2 = e + 3; }
                    } else {
                        #pragma unroll
                        for (int u = 0; u < 4; ++u) {
                            if (((bits >> u) & 1u) && e + u <= GMAX) {
                                float v = dens[e + u];
                                if (v > bv2) { bv2 = v; bi2 = e + u; }
                            }
                        }
                    }
                }
                #pragma unroll
                for (int off = 32; off > 0; off >>= 1) {
                    float ov = __shfl_down(bv2, off);
                    int   oi = __shfl_down(bi2, off);
                    if (ov > bv2 || (ov == bv2 && oi < bi2)) { bv2 = ov; bi2 = oi; }
                }
                if (lane == 0) { sval[s] = bv2; sidx[s] = bi2; }
            }
        }
        __syncthreads();
    }

    // ---- epilogue: one peak per thread ----
    if (tid < 4) {
        const int k   = tid;
        const float val = pval[k];
        const int   idx = pidx[k];
        const bool valid = val > VTH;
        float gx = 0.0f, gy = 0.0f, gz = 0.0f;
        if (valid) {
            gx = gxyz[idx * 3 + 0];
            gy = gxyz[idx * 3 + 1];
            gz = gxyz[idx * 3 + 2];
        }
        const float nm = nmask[n];
        const float* R = Rm + n * 9;
        const float* t = tp + n * 3;
        float wx = R[0] * gx + R[1] * gy + R[2] * gz + t[0];
        float wy = R[3] * gx + R[4] * gy + R[5] * gz + t[1];
        float wz = R[6] * gx + R[7] * gy + R[8] * gz + t[2];

        const size_t o3 = ((size_t)nc * 4 + k) * 3;
        out[o3 + 0] = gx * nm;                       // coords_local [1,128,4,4,3]
        out[o3 + 1] = gy * nm;
        out[o3 + 2] = gz * nm;
        out[6144 + o3 + 0] = wx * nm;                // coords_global
        out[6144 + o3 + 1] = wy * nm;
        out[6144 + o3 + 2] = wz * nm;
        const size_t o1 = (size_t)nc * 4 + k;
        out[12288 + o1] = (valid ? val : NEGV) * nm; // scores
        out[14336 + o1] = (valid && nm != 0.0f) ? 1.0f : 0.0f;  // mask
    }
}

extern "C" void kernel_launch(void* const* d_in, const int* in_sizes, int n_in,
                              void* d_out, int out_size, void* d_ws, size_t ws_size,
                              hipStream_t stream) {
    const float* density  = (const float*)d_in[0];  // [1,128,4,G] f32
    const float* grid_xyz = (const float*)d_in[1];  // [G,3] f32
    const float* Rm    = (const float*)d_in[4];     // [1,128,3,3] f32
    const float* tpos  = (const float*)d_in[5];     // [1,128,3] f32
    const float* nmask = (const float*)d_in[6];     // [1,128] f32
    float* out = (float*)d_out;                     // 16384 f32

    unsigned int* mask = (unsigned int*)d_ws;       // 8704 B

    build_mask<<<dim3(272), dim3(256), 0, stream>>>(grid_xyz, mask);
    fused_peaks<<<dim3(512), dim3(512), 0, stream>>>(density, grid_xyz, mask,
                                                     Rm, tpos, nmask, out);
}